// Round 6
// baseline (270.708 us; speedup 1.0000x reference)
//
#include <hip/hip_runtime.h>

#define NW 2048
#define NS 8192
#define NSL 128            // slices of 16 rows; slice = 16*2048 u16 = 64 KB LDS

typedef int            i32x4 __attribute__((ext_vector_type(4)));
typedef unsigned int   u32x4 __attribute__((ext_vector_type(4)));
typedef float          f32x4 __attribute__((ext_vector_type(4)));
typedef unsigned short u16x4 __attribute__((ext_vector_type(4)));

// ============================ PRIMARY PATH =================================
// P1: 8-bit fixed-point packed table: cell = (round(bias*255)<<8) | round(bigram*255).
__global__ __launch_bounds__(256) void build_table8_kernel(
    const f32x4* __restrict__ g, const f32x4* __restrict__ b,
    u16x4* __restrict__ tab4, int n4)
{
    int stride = gridDim.x * blockDim.x;
    for (int i = blockIdx.x * blockDim.x + threadIdx.x; i < n4; i += stride) {
        f32x4 gg = __builtin_nontemporal_load(&g[i]);
        f32x4 bb = __builtin_nontemporal_load(&b[i]);
        u16x4 o;
        o.x = (unsigned short)((__float2uint_rn(bb.x * 255.f) << 8) | __float2uint_rn(gg.x * 255.f));
        o.y = (unsigned short)((__float2uint_rn(bb.y * 255.f) << 8) | __float2uint_rn(gg.y * 255.f));
        o.z = (unsigned short)((__float2uint_rn(bb.z * 255.f) << 8) | __float2uint_rn(gg.z * 255.f));
        o.w = (unsigned short)((__float2uint_rn(bb.w * 255.f) << 8) | __float2uint_rn(gg.w * 255.f));
        __builtin_nontemporal_store(o, &tab4[i]);
    }
}

// P2: bucketing, wave-per-sample (all LDS wave-private; 4 cheap barriers).
// Output: per-sample bucketed keys (u16) + packed (cnt<<16)|off per (s,q).
__global__ __launch_bounds__(256) void bucket3_kernel(
    const i32x4* __restrict__ samples4,
    unsigned short* __restrict__ gkeys,        // NS * 2048
    unsigned* __restrict__ oc_s)               // NS * 128, (cnt<<16)|off
{
    __shared__ unsigned short srow[4][NW];
    __shared__ unsigned short kbuf[4][NW];
    __shared__ unsigned hist[4][NSL];
    __shared__ unsigned cur[4][NSL];
    const int t = threadIdx.x, w = t >> 6, l = t & 63;
    const int s = blockIdx.x * 4 + w;

    // load row (8 KB/wave, coalesced) -> u16 LDS
    const i32x4* rp = samples4 + (size_t)s * (NW / 4);
#pragma unroll
    for (int k = 0; k < 8; ++k) {
        i32x4 v = __builtin_nontemporal_load(&rp[l + 64 * k]);
        u16x4 o;
        o.x = (unsigned short)v.x; o.y = (unsigned short)v.y;
        o.z = (unsigned short)v.z; o.w = (unsigned short)v.w;
        ((u16x4*)srow[w])[l + 64 * k] = o;
    }
    hist[w][l] = 0; hist[w][l + 64] = 0;
    __syncthreads();

    // histogram (wave-private)
#pragma unroll
    for (int k = 0; k < 32; ++k) {
        int j = l + 64 * k;
        if (j < NW - 1) atomicAdd(&hist[w][srow[w][j] >> 4], 1u);
    }
    __syncthreads();

    // in-register inclusive scan of 128 bins (2x64 via shuffles)
    unsigned c0 = hist[w][l], c1 = hist[w][l + 64];
    unsigned x0 = c0, x1 = c1;
#pragma unroll
    for (int d = 1; d < 64; d <<= 1) {
        unsigned y0 = __shfl_up(x0, d);
        unsigned y1 = __shfl_up(x1, d);
        if (l >= d) { x0 += y0; x1 += y1; }
    }
    unsigned tot0 = __shfl(x0, 63);
    unsigned off0 = x0 - c0;
    unsigned off1 = tot0 + x1 - c1;
    cur[w][l] = off0; cur[w][l + 64] = off1;
    __syncthreads();

    // scatter keys into bucket order (wave-private kbuf)
#pragma unroll
    for (int k = 0; k < 32; ++k) {
        int j = l + 64 * k;
        if (j < NW - 1) {
            unsigned r = srow[w][j], c = srow[w][j + 1];
            unsigned pos = atomicAdd(&cur[w][r >> 4], 1u);
            kbuf[w][pos] = (unsigned short)(((r & 15u) << 11) | c);
        }
    }
    __syncthreads();

    // write out: keys (coalesced 16B/lane) + packed offcnt (coalesced)
#pragma unroll
    for (int k = 0; k < 4; ++k)
        __builtin_nontemporal_store(((u32x4*)kbuf[w])[l + 64 * k],
                                    &((u32x4*)(gkeys + (size_t)s * NW))[l + 64 * k]);
    oc_s[(size_t)s * NSL + l]      = (c0 << 16) | off0;
    oc_s[(size_t)s * NSL + l + 64] = (c1 << 16) | off1;
}

// P2b: transpose oc [s][q] -> [q][s] so the gather reads it coalesced.
// Tiles 64 samples x 32 q, LDS-padded.
__global__ __launch_bounds__(256) void transpose_oc_kernel(
    const unsigned* __restrict__ oc_s, unsigned* __restrict__ oc_q)
{
    __shared__ unsigned tile[64][33];
    const int t = threadIdx.x;
    const int s0 = blockIdx.x * 64, q0 = blockIdx.y * 32;
#pragma unroll
    for (int k = 0; k < 8; ++k) {
        int i = (t >> 5) + 8 * k, jq = t & 31;
        tile[i][jq] = oc_s[(size_t)(s0 + i) * NSL + q0 + jq];
    }
    __syncthreads();
#pragma unroll
    for (int k = 0; k < 8; ++k) {
        int qrow = (t >> 6) + 4 * k, scol = t & 63;
        oc_q[(size_t)(q0 + qrow) * NS + s0 + scol] = tile[scol][qrow];
    }
}

// P3: LDS-table gather. Block (q, chunk): slice q (64 KB) in LDS; lane owns
// one sample's packed offcnt (coalesced load); 16-lane groups process 4
// samples in parallel via shuffle-broadcast. No strided global loads.
__global__ __launch_bounds__(1024) void gather4_kernel(
    const unsigned short* __restrict__ tab,
    const unsigned short* __restrict__ gkeys,
    const unsigned* __restrict__ oc_q,
    unsigned long long* __restrict__ acc)
{
    __shared__ unsigned short stab[16 * NW];      // 64 KB
    const int q = blockIdx.x;
    const int chunk = blockIdx.y;
    const int t = threadIdx.x, w = t >> 6, l = t & 63;

    const u32x4* srcp = (const u32x4*)(tab + (size_t)q * 16 * NW);
    u32x4* dstp = (u32x4*)stab;
#pragma unroll
    for (int k = 0; k < 4; ++k)
        dstp[t + 1024 * k] = __builtin_nontemporal_load(&srcp[t + 1024 * k]);

    const int sbase = chunk * 1024 + w * 64;
    unsigned oc = oc_q[(size_t)q * NS + sbase + l];   // lane owns sample sbase+l
    __syncthreads();

    const int g = l >> 4, li = l & 15;
    for (int r = 0; r < 16; ++r) {
        int sid = r * 4 + g;                          // sample index within wave
        unsigned ocr = __shfl(oc, sid);
        unsigned off = ocr & 0xffffu, cnt = ocr >> 16;
        const unsigned short* kp = gkeys + (size_t)(sbase + sid) * NW + off;
        unsigned gs = 0, bs = 0;
        for (unsigned p = li; p < cnt; p += 16) {
            unsigned v = stab[kp[p]];
            gs += v & 0xffu;
            bs += v >> 8;
        }
#pragma unroll
        for (int o = 8; o; o >>= 1) {
            gs += __shfl_down(gs, o, 16);
            bs += __shfl_down(bs, o, 16);
        }
        if (li == 0)
            atomicAdd(&acc[sbase + sid],
                      ((unsigned long long)bs << 32) | (unsigned long long)gs);
    }
}

// P4: fp64 finalize; first/last words read straight from samples.
__global__ __launch_bounds__(1024) void finalize4_kernel(
    const float* __restrict__ bigram, const float* __restrict__ bias,
    const float* __restrict__ start, const float* __restrict__ endv,
    const unsigned long long* __restrict__ acc, const int* __restrict__ samples,
    float* __restrict__ out)
{
    const int t = threadIdx.x;
    double su = 0.0, sw = 0.0, diag = 0.0;
    for (int s = t; s < NS; s += 1024) {
        unsigned long long a = acc[s];
        int sf = samples[(size_t)s * NW];
        int sl = samples[(size_t)s * NW + NW - 1];
        double u = (double)(unsigned)(a & 0xffffffffu) * (1.0 / 255.0)
                 + (double)start[sf] + (double)endv[sl];
        double bb = (double)(unsigned)(a >> 32) * (1.0 / 255.0);
        su += u;
        sw += u * (u + bb);
    }
    for (int k = t; k < NW - 1; k += 1024) {
        size_t idx = (size_t)k * NW + (size_t)k + 1;
        diag += (double)bigram[idx] + (double)bias[idx];
    }
#pragma unroll
    for (int off = 32; off; off >>= 1) {
        su   += __shfl_down(su, off);
        sw   += __shfl_down(sw, off);
        diag += __shfl_down(diag, off);
    }
    __shared__ double s1[16], s2[16], s3[16];
    if ((t & 63) == 0) { int w = t >> 6; s1[w] = su; s2[w] = sw; s3[w] = diag; }
    __syncthreads();
    if (t == 0) {
        for (int w = 1; w < 16; ++w) { su += s1[w]; sw += s2[w]; diag += s3[w]; }
        double C = (double)start[0] + (double)endv[NW - 1] + diag;
        out[0] = (float)(sw / su - C);
    }
}

// ====================== FALLBACK (round-1 structure) ========================
__global__ __launch_bounds__(256) void interleave_kernel(
    const float* __restrict__ bigram, const float* __restrict__ bias,
    float2* __restrict__ comb)
{
    size_t total = (size_t)NW * NW;
    size_t stride = (size_t)gridDim.x * blockDim.x;
    for (size_t i = (size_t)blockIdx.x * blockDim.x + threadIdx.x; i < total; i += stride)
        comb[i] = make_float2(bigram[i], bias[i]);
}

template <bool USE_COMB>
__global__ __launch_bounds__(256) void sample_kernel(
    const float2* __restrict__ comb,
    const float* __restrict__ bigram, const float* __restrict__ bias,
    const float* __restrict__ start, const float* __restrict__ endv,
    const int* __restrict__ samples,
    float* __restrict__ u_out, float* __restrict__ b_out)
{
    __shared__ int srow[NW];
    __shared__ float su[4], sb[4];
    const int i = blockIdx.x;
    const int t = threadIdx.x;
    const int4* row4 = (const int4*)(samples + (size_t)i * NW);
    int4* srow4 = (int4*)srow;
    srow4[t]       = row4[t];
    srow4[t + 256] = row4[t + 256];
    __syncthreads();
    float u = 0.f, b = 0.f;
#pragma unroll
    for (int k = 0; k < 8; ++k) {
        int j = t + k * 256;
        if (j < NW - 1) {
            int r = srow[j], c = srow[j + 1];
            size_t idx = ((size_t)r << 11) + (size_t)c;
            if (USE_COMB) { float2 v = comb[idx]; u += v.x; b += v.y; }
            else          { u += bigram[idx]; b += bias[idx]; }
        }
    }
#pragma unroll
    for (int off = 32; off; off >>= 1) {
        u += __shfl_down(u, off);
        b += __shfl_down(b, off);
    }
    if ((t & 63) == 0) { su[t >> 6] = u; sb[t >> 6] = b; }
    __syncthreads();
    if (t == 0) {
        u = su[0] + su[1] + su[2] + su[3];
        b = sb[0] + sb[1] + sb[2] + sb[3];
        u += start[srow[0]] + endv[srow[NW - 1]];
        u_out[i] = u;
        b_out[i] = b;
    }
}

__global__ __launch_bounds__(1024) void finalize_kernel(
    const float* __restrict__ bigram, const float* __restrict__ bias,
    const float* __restrict__ start, const float* __restrict__ endv,
    const float* __restrict__ u_in, const float* __restrict__ b_in,
    float* __restrict__ out)
{
    const int t = threadIdx.x;
    double su = 0.0, sw = 0.0, diag = 0.0;
    for (int i = t; i < NS; i += 1024) {
        double u = (double)u_in[i];
        su += u;
        sw += u * (u + (double)b_in[i]);
    }
    for (int k = t; k < NW - 1; k += 1024) {
        size_t idx = (size_t)k * NW + (size_t)k + 1;
        diag += (double)bigram[idx] + (double)bias[idx];
    }
#pragma unroll
    for (int off = 32; off; off >>= 1) {
        su   += __shfl_down(su, off);
        sw   += __shfl_down(sw, off);
        diag += __shfl_down(diag, off);
    }
    __shared__ double s1[16], s2[16], s3[16];
    if ((t & 63) == 0) { int w = t >> 6; s1[w] = su; s2[w] = sw; s3[w] = diag; }
    __syncthreads();
    if (t == 0) {
        for (int w = 1; w < 16; ++w) { su += s1[w]; sw += s2[w]; diag += s3[w]; }
        double C = (double)start[0] + (double)endv[NW - 1] + diag;
        out[0] = (float)(sw / su - C);
    }
}

// ===========================================================================
extern "C" void kernel_launch(void* const* d_in, const int* in_sizes, int n_in,
                              void* d_out, int out_size, void* d_ws, size_t ws_size,
                              hipStream_t stream) {
    const float* bigram  = (const float*)d_in[0];
    const float* start   = (const float*)d_in[1];
    const float* endv    = (const float*)d_in[2];
    const float* bias    = (const float*)d_in[3];
    const int*   samples = (const int*)d_in[4];
    float* out = (float*)d_out;

    // primary ws layout
    size_t off = 0;
    size_t tab_off  = off; off += (size_t)NW * NW * 2;    // 8 MB u16 table
    off = (off + 255) & ~(size_t)255;
    size_t keys_off = off; off += (size_t)NS * NW * 2;    // 32 MB u16 keys
    off = (off + 255) & ~(size_t)255;
    size_t ocs_off  = off; off += (size_t)NS * NSL * 4;   // 4 MB oc sample-major
    off = (off + 255) & ~(size_t)255;
    size_t ocq_off  = off; off += (size_t)NS * NSL * 4;   // 4 MB oc slice-major
    off = (off + 255) & ~(size_t)255;
    size_t acc_off  = off; off += (size_t)NS * 8;         // 64 KB packed acc
    size_t need_primary = off;

    if (ws_size >= need_primary) {
        unsigned short*     tab   = (unsigned short*)((char*)d_ws + tab_off);
        unsigned short*     gkeys = (unsigned short*)((char*)d_ws + keys_off);
        unsigned*           oc_s  = (unsigned*)((char*)d_ws + ocs_off);
        unsigned*           oc_q  = (unsigned*)((char*)d_ws + ocq_off);
        unsigned long long* acc   = (unsigned long long*)((char*)d_ws + acc_off);

        hipMemsetAsync(acc, 0, (size_t)NS * 8, stream);
        build_table8_kernel<<<2048, 256, 0, stream>>>(
            (const f32x4*)bigram, (const f32x4*)bias, (u16x4*)tab, NW * NW / 4);
        bucket3_kernel<<<NS / 4, 256, 0, stream>>>(
            (const i32x4*)samples, gkeys, oc_s);
        transpose_oc_kernel<<<dim3(NS / 64, NSL / 32), 256, 0, stream>>>(oc_s, oc_q);
        gather4_kernel<<<dim3(NSL, NS / 1024), 1024, 0, stream>>>(
            tab, gkeys, oc_q, acc);
        finalize4_kernel<<<1, 1024, 0, stream>>>(
            bigram, bias, start, endv, acc, samples, out);
        return;
    }

    // fallback: round-1 structure
    float* u_out = (float*)d_ws;
    float* b_out = u_out + NS;
    size_t comb_off = ((size_t)NS * 2 * sizeof(float) + 255) & ~(size_t)255;
    size_t comb_bytes = (size_t)NW * NW * sizeof(float2);
    bool use_comb = (ws_size >= comb_off + comb_bytes);
    if (use_comb) {
        float2* comb = (float2*)((char*)d_ws + comb_off);
        interleave_kernel<<<4096, 256, 0, stream>>>(bigram, bias, comb);
        sample_kernel<true><<<NS, 256, 0, stream>>>(comb, bigram, bias, start, endv,
                                                    samples, u_out, b_out);
    } else {
        sample_kernel<false><<<NS, 256, 0, stream>>>(nullptr, bigram, bias, start, endv,
                                                     samples, u_out, b_out);
    }
    finalize_kernel<<<1, 1024, 0, stream>>>(bigram, bias, start, endv, u_out, b_out, out);
}

// Round 7
// 220.152 us; speedup vs baseline: 1.2296x; 1.2296x over previous
//
#include <hip/hip_runtime.h>

#define NW 2048
#define NS 8192
#define NSL 128            // slices of 16 rows; slice = 16*2048 u16 = 64 KB LDS

typedef int            i32x4 __attribute__((ext_vector_type(4)));
typedef unsigned int   u32x4 __attribute__((ext_vector_type(4)));
typedef float          f32x4 __attribute__((ext_vector_type(4)));
typedef unsigned short u16x4 __attribute__((ext_vector_type(4)));

// ============================ PRIMARY PATH =================================
// P1: 8-bit fixed-point packed table: cell = (round(bias*255)<<8) | round(bigram*255).
__global__ __launch_bounds__(256) void build_table8_kernel(
    const f32x4* __restrict__ g, const f32x4* __restrict__ b,
    u16x4* __restrict__ tab4, int n4)
{
    int stride = gridDim.x * blockDim.x;
    for (int i = blockIdx.x * blockDim.x + threadIdx.x; i < n4; i += stride) {
        f32x4 gg = __builtin_nontemporal_load(&g[i]);
        f32x4 bb = __builtin_nontemporal_load(&b[i]);
        u16x4 o;
        o.x = (unsigned short)((__float2uint_rn(bb.x * 255.f) << 8) | __float2uint_rn(gg.x * 255.f));
        o.y = (unsigned short)((__float2uint_rn(bb.y * 255.f) << 8) | __float2uint_rn(gg.y * 255.f));
        o.z = (unsigned short)((__float2uint_rn(bb.z * 255.f) << 8) | __float2uint_rn(gg.z * 255.f));
        o.w = (unsigned short)((__float2uint_rn(bb.w * 255.f) << 8) | __float2uint_rn(gg.w * 255.f));
        __builtin_nontemporal_store(o, &tab4[i]);
    }
}

// P2: bucketing, wave-per-sample (all LDS wave-private; 4 cheap barriers).
// Output: per-sample bucketed keys (u16), packed (cnt<<16)|off per (s,q),
// and first/last words.
__global__ __launch_bounds__(256) void bucket3_kernel(
    const i32x4* __restrict__ samples4,
    unsigned short* __restrict__ gkeys,        // NS * 2048
    unsigned* __restrict__ oc_s,               // NS * 128, (cnt<<16)|off
    int* __restrict__ fl)                      // NS * 2
{
    __shared__ unsigned short srow[4][NW];
    __shared__ unsigned short kbuf[4][NW];
    __shared__ unsigned hist[4][NSL];
    __shared__ unsigned cur[4][NSL];
    const int t = threadIdx.x, w = t >> 6, l = t & 63;
    const int s = blockIdx.x * 4 + w;

    // load row (8 KB/wave, coalesced) -> u16 LDS
    const i32x4* rp = samples4 + (size_t)s * (NW / 4);
#pragma unroll
    for (int k = 0; k < 8; ++k) {
        i32x4 v = __builtin_nontemporal_load(&rp[l + 64 * k]);
        u16x4 o;
        o.x = (unsigned short)v.x; o.y = (unsigned short)v.y;
        o.z = (unsigned short)v.z; o.w = (unsigned short)v.w;
        ((u16x4*)srow[w])[l + 64 * k] = o;
    }
    hist[w][l] = 0; hist[w][l + 64] = 0;
    __syncthreads();

    // histogram (wave-private)
#pragma unroll
    for (int k = 0; k < 32; ++k) {
        int j = l + 64 * k;
        if (j < NW - 1) atomicAdd(&hist[w][srow[w][j] >> 4], 1u);
    }
    __syncthreads();

    // in-register inclusive scan of 128 bins (2x64 via shuffles)
    unsigned c0 = hist[w][l], c1 = hist[w][l + 64];
    unsigned x0 = c0, x1 = c1;
#pragma unroll
    for (int d = 1; d < 64; d <<= 1) {
        unsigned y0 = __shfl_up(x0, d);
        unsigned y1 = __shfl_up(x1, d);
        if (l >= d) { x0 += y0; x1 += y1; }
    }
    unsigned tot0 = __shfl(x0, 63);
    unsigned off0 = x0 - c0;
    unsigned off1 = tot0 + x1 - c1;
    cur[w][l] = off0; cur[w][l + 64] = off1;
    __syncthreads();

    // scatter keys into bucket order (wave-private kbuf)
#pragma unroll
    for (int k = 0; k < 32; ++k) {
        int j = l + 64 * k;
        if (j < NW - 1) {
            unsigned r = srow[w][j], c = srow[w][j + 1];
            unsigned pos = atomicAdd(&cur[w][r >> 4], 1u);
            kbuf[w][pos] = (unsigned short)(((r & 15u) << 11) | c);
        }
    }
    __syncthreads();

    // write out: keys (coalesced 16B/lane) + packed offcnt (coalesced)
#pragma unroll
    for (int k = 0; k < 4; ++k)
        __builtin_nontemporal_store(((u32x4*)kbuf[w])[l + 64 * k],
                                    &((u32x4*)(gkeys + (size_t)s * NW))[l + 64 * k]);
    oc_s[(size_t)s * NSL + l]      = (c0 << 16) | off0;
    oc_s[(size_t)s * NSL + l + 64] = (c1 << 16) | off1;
    if (l == 0) { fl[2 * s] = (int)srow[w][0]; fl[2 * s + 1] = (int)srow[w][NW - 1]; }
}

// P2b: transpose oc [s][q] -> [q][s] so the gather reads it coalesced.
__global__ __launch_bounds__(256) void transpose_oc_kernel(
    const unsigned* __restrict__ oc_s, unsigned* __restrict__ oc_q)
{
    __shared__ unsigned tile[64][33];
    const int t = threadIdx.x;
    const int s0 = blockIdx.x * 64, q0 = blockIdx.y * 32;
#pragma unroll
    for (int k = 0; k < 8; ++k) {
        int i = (t >> 5) + 8 * k, jq = t & 31;
        tile[i][jq] = oc_s[(size_t)(s0 + i) * NSL + q0 + jq];
    }
    __syncthreads();
#pragma unroll
    for (int k = 0; k < 8; ++k) {
        int qrow = (t >> 6) + 4 * k, scol = t & 63;
        oc_q[(size_t)(q0 + qrow) * NS + s0 + scol] = tile[scol][qrow];
    }
}

// P3: LDS-table gather. Block (q, chunk) handles bin = ((q&7)<<4)|(q>>3):
// block linear id % 8 == q % 8 -> XCD x owns contiguous bins [16x,16x+16),
// so (a) adjacent key segments sharing a 64B line are read by the same XCD,
// (b) per-XCD table working set is a contiguous 1MB, L2-resident, and the
// slice staging (PLAIN cacheable loads -- L2 reuse across the 8 chunks) hits
// HBM only once per slice.
__global__ __launch_bounds__(1024) void gather5_kernel(
    const unsigned short* __restrict__ tab,
    const unsigned short* __restrict__ gkeys,
    const unsigned* __restrict__ oc_q,
    unsigned long long* __restrict__ acc)
{
    __shared__ unsigned short stab[16 * NW];      // 64 KB
    const int q = blockIdx.x;
    const int bin = ((q & 7) << 4) | (q >> 3);    // XCD-contiguous bin mapping
    const int chunk = blockIdx.y;
    const int t = threadIdx.x, w = t >> 6, l = t & 63;

    const u32x4* srcp = (const u32x4*)(tab + (size_t)bin * 16 * NW);
    u32x4* dstp = (u32x4*)stab;
#pragma unroll
    for (int k = 0; k < 4; ++k)
        dstp[t + 1024 * k] = srcp[t + 1024 * k];  // cacheable: 7/8 chunks hit L2

    const int sbase = chunk * 1024 + w * 64;
    unsigned oc = oc_q[(size_t)bin * NS + sbase + l];   // lane owns sample sbase+l
    __syncthreads();

    const int g = l >> 4, li = l & 15;
    for (int r = 0; r < 16; ++r) {
        int sid = r * 4 + g;                          // sample index within wave
        unsigned ocr = __shfl(oc, sid);
        unsigned off = ocr & 0xffffu, cnt = ocr >> 16;
        const unsigned short* kp = gkeys + (size_t)(sbase + sid) * NW + off;
        unsigned gs = 0, bs = 0;
        for (unsigned p = li; p < cnt; p += 16) {
            unsigned v = stab[kp[p]];
            gs += v & 0xffu;
            bs += v >> 8;
        }
#pragma unroll
        for (int o = 8; o; o >>= 1) {
            gs += __shfl_down(gs, o, 16);
            bs += __shfl_down(bs, o, 16);
        }
        if (li == 0)
            atomicAdd(&acc[sbase + sid],
                      ((unsigned long long)bs << 32) | (unsigned long long)gs);
    }
}

// P4: fp64 finalize (fl-based: coalesced).
__global__ __launch_bounds__(1024) void finalize5_kernel(
    const float* __restrict__ bigram, const float* __restrict__ bias,
    const float* __restrict__ start, const float* __restrict__ endv,
    const unsigned long long* __restrict__ acc, const int* __restrict__ fl,
    float* __restrict__ out)
{
    const int t = threadIdx.x;
    double su = 0.0, sw = 0.0, diag = 0.0;
    for (int s = t; s < NS; s += 1024) {
        unsigned long long a = acc[s];
        double u = (double)(unsigned)(a & 0xffffffffu) * (1.0 / 255.0)
                 + (double)start[fl[2 * s]]
                 + (double)endv[fl[2 * s + 1]];
        double bb = (double)(unsigned)(a >> 32) * (1.0 / 255.0);
        su += u;
        sw += u * (u + bb);
    }
    for (int k = t; k < NW - 1; k += 1024) {
        size_t idx = (size_t)k * NW + (size_t)k + 1;
        diag += (double)bigram[idx] + (double)bias[idx];
    }
#pragma unroll
    for (int off = 32; off; off >>= 1) {
        su   += __shfl_down(su, off);
        sw   += __shfl_down(sw, off);
        diag += __shfl_down(diag, off);
    }
    __shared__ double s1[16], s2[16], s3[16];
    if ((t & 63) == 0) { int w = t >> 6; s1[w] = su; s2[w] = sw; s3[w] = diag; }
    __syncthreads();
    if (t == 0) {
        for (int w = 1; w < 16; ++w) { su += s1[w]; sw += s2[w]; diag += s3[w]; }
        double C = (double)start[0] + (double)endv[NW - 1] + diag;
        out[0] = (float)(sw / su - C);
    }
}

// ====================== FALLBACK (round-1 structure) ========================
__global__ __launch_bounds__(256) void interleave_kernel(
    const float* __restrict__ bigram, const float* __restrict__ bias,
    float2* __restrict__ comb)
{
    size_t total = (size_t)NW * NW;
    size_t stride = (size_t)gridDim.x * blockDim.x;
    for (size_t i = (size_t)blockIdx.x * blockDim.x + threadIdx.x; i < total; i += stride)
        comb[i] = make_float2(bigram[i], bias[i]);
}

template <bool USE_COMB>
__global__ __launch_bounds__(256) void sample_kernel(
    const float2* __restrict__ comb,
    const float* __restrict__ bigram, const float* __restrict__ bias,
    const float* __restrict__ start, const float* __restrict__ endv,
    const int* __restrict__ samples,
    float* __restrict__ u_out, float* __restrict__ b_out)
{
    __shared__ int srow[NW];
    __shared__ float su[4], sb[4];
    const int i = blockIdx.x;
    const int t = threadIdx.x;
    const int4* row4 = (const int4*)(samples + (size_t)i * NW);
    int4* srow4 = (int4*)srow;
    srow4[t]       = row4[t];
    srow4[t + 256] = row4[t + 256];
    __syncthreads();
    float u = 0.f, b = 0.f;
#pragma unroll
    for (int k = 0; k < 8; ++k) {
        int j = t + k * 256;
        if (j < NW - 1) {
            int r = srow[j], c = srow[j + 1];
            size_t idx = ((size_t)r << 11) + (size_t)c;
            if (USE_COMB) { float2 v = comb[idx]; u += v.x; b += v.y; }
            else          { u += bigram[idx]; b += bias[idx]; }
        }
    }
#pragma unroll
    for (int off = 32; off; off >>= 1) {
        u += __shfl_down(u, off);
        b += __shfl_down(b, off);
    }
    if ((t & 63) == 0) { su[t >> 6] = u; sb[t >> 6] = b; }
    __syncthreads();
    if (t == 0) {
        u = su[0] + su[1] + su[2] + su[3];
        b = sb[0] + sb[1] + sb[2] + sb[3];
        u += start[srow[0]] + endv[srow[NW - 1]];
        u_out[i] = u;
        b_out[i] = b;
    }
}

__global__ __launch_bounds__(1024) void finalize_kernel(
    const float* __restrict__ bigram, const float* __restrict__ bias,
    const float* __restrict__ start, const float* __restrict__ endv,
    const float* __restrict__ u_in, const float* __restrict__ b_in,
    float* __restrict__ out)
{
    const int t = threadIdx.x;
    double su = 0.0, sw = 0.0, diag = 0.0;
    for (int i = t; i < NS; i += 1024) {
        double u = (double)u_in[i];
        su += u;
        sw += u * (u + (double)b_in[i]);
    }
    for (int k = t; k < NW - 1; k += 1024) {
        size_t idx = (size_t)k * NW + (size_t)k + 1;
        diag += (double)bigram[idx] + (double)bias[idx];
    }
#pragma unroll
    for (int off = 32; off; off >>= 1) {
        su   += __shfl_down(su, off);
        sw   += __shfl_down(sw, off);
        diag += __shfl_down(diag, off);
    }
    __shared__ double s1[16], s2[16], s3[16];
    if ((t & 63) == 0) { int w = t >> 6; s1[w] = su; s2[w] = sw; s3[w] = diag; }
    __syncthreads();
    if (t == 0) {
        for (int w = 1; w < 16; ++w) { su += s1[w]; sw += s2[w]; diag += s3[w]; }
        double C = (double)start[0] + (double)endv[NW - 1] + diag;
        out[0] = (float)(sw / su - C);
    }
}

// ===========================================================================
extern "C" void kernel_launch(void* const* d_in, const int* in_sizes, int n_in,
                              void* d_out, int out_size, void* d_ws, size_t ws_size,
                              hipStream_t stream) {
    const float* bigram  = (const float*)d_in[0];
    const float* start   = (const float*)d_in[1];
    const float* endv    = (const float*)d_in[2];
    const float* bias    = (const float*)d_in[3];
    const int*   samples = (const int*)d_in[4];
    float* out = (float*)d_out;

    // primary ws layout
    size_t off = 0;
    size_t tab_off  = off; off += (size_t)NW * NW * 2;    // 8 MB u16 table
    off = (off + 255) & ~(size_t)255;
    size_t keys_off = off; off += (size_t)NS * NW * 2;    // 32 MB u16 keys
    off = (off + 255) & ~(size_t)255;
    size_t ocs_off  = off; off += (size_t)NS * NSL * 4;   // 4 MB oc sample-major
    off = (off + 255) & ~(size_t)255;
    size_t ocq_off  = off; off += (size_t)NS * NSL * 4;   // 4 MB oc slice-major
    off = (off + 255) & ~(size_t)255;
    size_t fl_off   = off; off += (size_t)NS * 2 * 4;     // 64 KB first/last
    off = (off + 255) & ~(size_t)255;
    size_t acc_off  = off; off += (size_t)NS * 8;         // 64 KB packed acc
    size_t need_primary = off;

    if (ws_size >= need_primary) {
        unsigned short*     tab   = (unsigned short*)((char*)d_ws + tab_off);
        unsigned short*     gkeys = (unsigned short*)((char*)d_ws + keys_off);
        unsigned*           oc_s  = (unsigned*)((char*)d_ws + ocs_off);
        unsigned*           oc_q  = (unsigned*)((char*)d_ws + ocq_off);
        int*                fl    = (int*)((char*)d_ws + fl_off);
        unsigned long long* acc   = (unsigned long long*)((char*)d_ws + acc_off);

        hipMemsetAsync(acc, 0, (size_t)NS * 8, stream);
        build_table8_kernel<<<2048, 256, 0, stream>>>(
            (const f32x4*)bigram, (const f32x4*)bias, (u16x4*)tab, NW * NW / 4);
        bucket3_kernel<<<NS / 4, 256, 0, stream>>>(
            (const i32x4*)samples, gkeys, oc_s, fl);
        transpose_oc_kernel<<<dim3(NS / 64, NSL / 32), 256, 0, stream>>>(oc_s, oc_q);
        gather5_kernel<<<dim3(NSL, NS / 1024), 1024, 0, stream>>>(
            tab, gkeys, oc_q, acc);
        finalize5_kernel<<<1, 1024, 0, stream>>>(
            bigram, bias, start, endv, acc, fl, out);
        return;
    }

    // fallback: round-1 structure
    float* u_out = (float*)d_ws;
    float* b_out = u_out + NS;
    size_t comb_off = ((size_t)NS * 2 * sizeof(float) + 255) & ~(size_t)255;
    size_t comb_bytes = (size_t)NW * NW * sizeof(float2);
    bool use_comb = (ws_size >= comb_off + comb_bytes);
    if (use_comb) {
        float2* comb = (float2*)((char*)d_ws + comb_off);
        interleave_kernel<<<4096, 256, 0, stream>>>(bigram, bias, comb);
        sample_kernel<true><<<NS, 256, 0, stream>>>(comb, bigram, bias, start, endv,
                                                    samples, u_out, b_out);
    } else {
        sample_kernel<false><<<NS, 256, 0, stream>>>(nullptr, bigram, bias, start, endv,
                                                     samples, u_out, b_out);
    }
    finalize_kernel<<<1, 1024, 0, stream>>>(bigram, bias, start, endv, u_out, b_out, out);
}

// Round 9
// 185.341 us; speedup vs baseline: 1.4606x; 1.1878x over previous
//
#include <hip/hip_runtime.h>

#define NW 2048
#define NS 8192
#define NSL 128            // slices of 16 rows; slice = 16*2048 u16 = 64 KB LDS

typedef int            i32x4 __attribute__((ext_vector_type(4)));
typedef unsigned int   u32x4 __attribute__((ext_vector_type(4)));
typedef float          f32x4 __attribute__((ext_vector_type(4)));
typedef unsigned short u16x4 __attribute__((ext_vector_type(4)));

// 16-lane sum reduce via DPP row_shr (VALU-only).
// row_shr:N moves lane i-N -> lane i, so the FULL sum lands in lane 15 of
// each 16-lane row (AMD's canonical DPP reduce reads lane 63 for wave64).
__device__ __forceinline__ unsigned red16(unsigned x) {
    x += (unsigned)__builtin_amdgcn_update_dpp(0, (int)x, 0x111, 0xF, 0xF, true); // row_shr:1
    x += (unsigned)__builtin_amdgcn_update_dpp(0, (int)x, 0x112, 0xF, 0xF, true); // row_shr:2
    x += (unsigned)__builtin_amdgcn_update_dpp(0, (int)x, 0x114, 0xF, 0xF, true); // row_shr:4
    x += (unsigned)__builtin_amdgcn_update_dpp(0, (int)x, 0x118, 0xF, 0xF, true); // row_shr:8
    return x;   // valid in lane 15 of each row
}

// ============================ PRIMARY PATH =================================
// P1: 8-bit fixed-point packed table: cell = (round(bias*255)<<8) | round(bigram*255).
__global__ __launch_bounds__(256) void build_table8_kernel(
    const f32x4* __restrict__ g, const f32x4* __restrict__ b,
    u16x4* __restrict__ tab4, int n4)
{
    int stride = gridDim.x * blockDim.x;
    for (int i = blockIdx.x * blockDim.x + threadIdx.x; i < n4; i += stride) {
        f32x4 gg = __builtin_nontemporal_load(&g[i]);
        f32x4 bb = __builtin_nontemporal_load(&b[i]);
        u16x4 o;
        o.x = (unsigned short)((__float2uint_rn(bb.x * 255.f) << 8) | __float2uint_rn(gg.x * 255.f));
        o.y = (unsigned short)((__float2uint_rn(bb.y * 255.f) << 8) | __float2uint_rn(gg.y * 255.f));
        o.z = (unsigned short)((__float2uint_rn(bb.z * 255.f) << 8) | __float2uint_rn(gg.z * 255.f));
        o.w = (unsigned short)((__float2uint_rn(bb.w * 255.f) << 8) | __float2uint_rn(gg.w * 255.f));
        __builtin_nontemporal_store(o, &tab4[i]);
    }
}

// P2: bucketing, wave-per-sample (all LDS wave-private).
__global__ __launch_bounds__(256) void bucket3_kernel(
    const i32x4* __restrict__ samples4,
    unsigned short* __restrict__ gkeys,        // NS * 2048
    unsigned* __restrict__ oc_s,               // NS * 128, (cnt<<16)|off
    int* __restrict__ fl)                      // NS * 2
{
    __shared__ unsigned short srow[4][NW];
    __shared__ unsigned short kbuf[4][NW];
    __shared__ unsigned hist[4][NSL];
    __shared__ unsigned cur[4][NSL];
    const int t = threadIdx.x, w = t >> 6, l = t & 63;
    const int s = blockIdx.x * 4 + w;

    const i32x4* rp = samples4 + (size_t)s * (NW / 4);
#pragma unroll
    for (int k = 0; k < 8; ++k) {
        i32x4 v = __builtin_nontemporal_load(&rp[l + 64 * k]);
        u16x4 o;
        o.x = (unsigned short)v.x; o.y = (unsigned short)v.y;
        o.z = (unsigned short)v.z; o.w = (unsigned short)v.w;
        ((u16x4*)srow[w])[l + 64 * k] = o;
    }
    hist[w][l] = 0; hist[w][l + 64] = 0;
    __syncthreads();

#pragma unroll
    for (int k = 0; k < 32; ++k) {
        int j = l + 64 * k;
        if (j < NW - 1) atomicAdd(&hist[w][srow[w][j] >> 4], 1u);
    }
    __syncthreads();

    unsigned c0 = hist[w][l], c1 = hist[w][l + 64];
    unsigned x0 = c0, x1 = c1;
#pragma unroll
    for (int d = 1; d < 64; d <<= 1) {
        unsigned y0 = __shfl_up(x0, d);
        unsigned y1 = __shfl_up(x1, d);
        if (l >= d) { x0 += y0; x1 += y1; }
    }
    unsigned tot0 = __shfl(x0, 63);
    unsigned off0 = x0 - c0;
    unsigned off1 = tot0 + x1 - c1;
    cur[w][l] = off0; cur[w][l + 64] = off1;
    __syncthreads();

#pragma unroll
    for (int k = 0; k < 32; ++k) {
        int j = l + 64 * k;
        if (j < NW - 1) {
            unsigned r = srow[w][j], c = srow[w][j + 1];
            unsigned pos = atomicAdd(&cur[w][r >> 4], 1u);
            kbuf[w][pos] = (unsigned short)(((r & 15u) << 11) | c);
        }
    }
    __syncthreads();

#pragma unroll
    for (int k = 0; k < 4; ++k)
        __builtin_nontemporal_store(((u32x4*)kbuf[w])[l + 64 * k],
                                    &((u32x4*)(gkeys + (size_t)s * NW))[l + 64 * k]);
    oc_s[(size_t)s * NSL + l]      = (c0 << 16) | off0;
    oc_s[(size_t)s * NSL + l + 64] = (c1 << 16) | off1;
    if (l == 0) { fl[2 * s] = (int)srow[w][0]; fl[2 * s + 1] = (int)srow[w][NW - 1]; }
}

// P2b: transpose oc [s][q] -> [q][s].
__global__ __launch_bounds__(256) void transpose_oc_kernel(
    const unsigned* __restrict__ oc_s, unsigned* __restrict__ oc_q)
{
    __shared__ unsigned tile[64][33];
    const int t = threadIdx.x;
    const int s0 = blockIdx.x * 64, q0 = blockIdx.y * 32;
#pragma unroll
    for (int k = 0; k < 8; ++k) {
        int i = (t >> 5) + 8 * k, jq = t & 31;
        tile[i][jq] = oc_s[(size_t)(s0 + i) * NSL + q0 + jq];
    }
    __syncthreads();
#pragma unroll
    for (int k = 0; k < 8; ++k) {
        int qrow = (t >> 6) + 4 * k, scol = t & 63;
        oc_q[(size_t)(q0 + qrow) * NS + s0 + scol] = tile[scol][qrow];
    }
}

// P3: LDS-table gather, latency-flattened:
//  - batch-prefetch 8 rounds of ocr (independent bpermutes) + 8 key loads
//    (independent vmem) so latencies overlap;
//  - 16-lane reduce via DPP row_shr adds (VALU); sum valid in lane 15;
//  - fire-and-forget u64 atomic from lane 15.
__global__ __launch_bounds__(1024) void gather6_kernel(
    const unsigned short* __restrict__ tab,
    const unsigned short* __restrict__ gkeys,
    const unsigned* __restrict__ oc_q,
    unsigned long long* __restrict__ acc)
{
    __shared__ unsigned short stab[16 * NW];      // 64 KB
    const int q = blockIdx.x;
    const int bin = ((q & 7) << 4) | (q >> 3);    // XCD-contiguous bin mapping
    const int chunk = blockIdx.y;
    const int t = threadIdx.x, w = t >> 6, l = t & 63;

    const u32x4* srcp = (const u32x4*)(tab + (size_t)bin * 16 * NW);
    u32x4* dstp = (u32x4*)stab;
#pragma unroll
    for (int k = 0; k < 4; ++k)
        dstp[t + 1024 * k] = srcp[t + 1024 * k];  // cacheable: L2 reuse across chunks

    const int sbase = chunk * 1024 + w * 64;
    unsigned oc = oc_q[(size_t)bin * NS + sbase + l];
    __syncthreads();

    const int g = l >> 4, li = l & 15;
    const unsigned short* keyrow = gkeys + (size_t)sbase * NW;

#pragma unroll
    for (int batch = 0; batch < 2; ++batch) {
        unsigned ocr[8];
        unsigned short key[8];
        // A: 8 independent broadcasts
#pragma unroll
        for (int r8 = 0; r8 < 8; ++r8)
            ocr[r8] = __shfl(oc, (batch * 8 + r8) * 4 + g);
        // B: 8 independent predicated key loads (latencies overlap)
#pragma unroll
        for (int r8 = 0; r8 < 8; ++r8) {
            int sid = (batch * 8 + r8) * 4 + g;
            unsigned off = ocr[r8] & 0xffffu, cnt = ocr[r8] >> 16;
            key[r8] = (li < (int)cnt)
                      ? keyrow[(size_t)sid * NW + off + li] : (unsigned short)0;
        }
        // C: consume
#pragma unroll
        for (int r8 = 0; r8 < 8; ++r8) {
            int sid = (batch * 8 + r8) * 4 + g;
            unsigned off = ocr[r8] & 0xffffu, cnt = ocr[r8] >> 16;
            unsigned gs = 0, bs = 0;
            if (li < (int)cnt) {
                unsigned v = stab[key[r8]];
                gs = v & 0xffu; bs = v >> 8;
            }
            for (unsigned p = (unsigned)li + 16; p < cnt; p += 16) {
                unsigned v = stab[keyrow[(size_t)sid * NW + off + p]];
                gs += v & 0xffu; bs += v >> 8;
            }
            gs = red16(gs);
            bs = red16(bs);
            if (li == 15)     // DPP row_shr sum completes in lane 15
                atomicAdd(&acc[sbase + sid],
                          ((unsigned long long)bs << 32) | (unsigned long long)gs);
        }
    }
}

// P4a: parallel finalize partials — 32 blocks x 256 thr, one sample/thread.
__global__ __launch_bounds__(256) void finalize_part_kernel(
    const float* __restrict__ bigram, const float* __restrict__ bias,
    const float* __restrict__ start, const float* __restrict__ endv,
    const unsigned long long* __restrict__ acc, const int* __restrict__ fl,
    double* __restrict__ part)
{
    const int b = blockIdx.x, t = threadIdx.x;
    const int s = b * 256 + t;
    unsigned long long a = acc[s];
    double u = (double)(unsigned)(a & 0xffffffffu) * (1.0 / 255.0)
             + (double)start[fl[2 * s]] + (double)endv[fl[2 * s + 1]];
    double bb = (double)(unsigned)(a >> 32) * (1.0 / 255.0);
    double su = u, sw = u * (u + bb), diag = 0.0;
    if (s < NW - 1) {
        size_t idx = (size_t)s * NW + (size_t)s + 1;
        diag = (double)bigram[idx] + (double)bias[idx];
    }
#pragma unroll
    for (int o = 32; o; o >>= 1) {
        su   += __shfl_down(su, o);
        sw   += __shfl_down(sw, o);
        diag += __shfl_down(diag, o);
    }
    __shared__ double sh[3][4];
    if ((t & 63) == 0) { int w = t >> 6; sh[0][w] = su; sh[1][w] = sw; sh[2][w] = diag; }
    __syncthreads();
    if (t == 0) {
        su   = sh[0][0] + sh[0][1] + sh[0][2] + sh[0][3];
        sw   = sh[1][0] + sh[1][1] + sh[1][2] + sh[1][3];
        diag = sh[2][0] + sh[2][1] + sh[2][2] + sh[2][3];
        part[3 * b] = su; part[3 * b + 1] = sw; part[3 * b + 2] = diag;
    }
}

// P4b: combine 32 partial triples.
__global__ __launch_bounds__(64) void finalize_final_kernel(
    const float* __restrict__ start, const float* __restrict__ endv,
    const double* __restrict__ part, float* __restrict__ out)
{
    if (threadIdx.x == 0) {
        double su = 0.0, sw = 0.0, diag = 0.0;
        for (int b = 0; b < 32; ++b) {
            su += part[3 * b]; sw += part[3 * b + 1]; diag += part[3 * b + 2];
        }
        double C = (double)start[0] + (double)endv[NW - 1] + diag;
        out[0] = (float)(sw / su - C);
    }
}

// ====================== FALLBACK (round-1 structure) ========================
__global__ __launch_bounds__(256) void interleave_kernel(
    const float* __restrict__ bigram, const float* __restrict__ bias,
    float2* __restrict__ comb)
{
    size_t total = (size_t)NW * NW;
    size_t stride = (size_t)gridDim.x * blockDim.x;
    for (size_t i = (size_t)blockIdx.x * blockDim.x + threadIdx.x; i < total; i += stride)
        comb[i] = make_float2(bigram[i], bias[i]);
}

template <bool USE_COMB>
__global__ __launch_bounds__(256) void sample_kernel(
    const float2* __restrict__ comb,
    const float* __restrict__ bigram, const float* __restrict__ bias,
    const float* __restrict__ start, const float* __restrict__ endv,
    const int* __restrict__ samples,
    float* __restrict__ u_out, float* __restrict__ b_out)
{
    __shared__ int srow[NW];
    __shared__ float su[4], sb[4];
    const int i = blockIdx.x;
    const int t = threadIdx.x;
    const int4* row4 = (const int4*)(samples + (size_t)i * NW);
    int4* srow4 = (int4*)srow;
    srow4[t]       = row4[t];
    srow4[t + 256] = row4[t + 256];
    __syncthreads();
    float u = 0.f, b = 0.f;
#pragma unroll
    for (int k = 0; k < 8; ++k) {
        int j = t + k * 256;
        if (j < NW - 1) {
            int r = srow[j], c = srow[j + 1];
            size_t idx = ((size_t)r << 11) + (size_t)c;
            if (USE_COMB) { float2 v = comb[idx]; u += v.x; b += v.y; }
            else          { u += bigram[idx]; b += bias[idx]; }
        }
    }
#pragma unroll
    for (int off = 32; off; off >>= 1) {
        u += __shfl_down(u, off);
        b += __shfl_down(b, off);
    }
    if ((t & 63) == 0) { su[t >> 6] = u; sb[t >> 6] = b; }
    __syncthreads();
    if (t == 0) {
        u = su[0] + su[1] + su[2] + su[3];
        b = sb[0] + sb[1] + sb[2] + sb[3];
        u += start[srow[0]] + endv[srow[NW - 1]];
        u_out[i] = u;
        b_out[i] = b;
    }
}

__global__ __launch_bounds__(1024) void finalize_kernel(
    const float* __restrict__ bigram, const float* __restrict__ bias,
    const float* __restrict__ start, const float* __restrict__ endv,
    const float* __restrict__ u_in, const float* __restrict__ b_in,
    float* __restrict__ out)
{
    const int t = threadIdx.x;
    double su = 0.0, sw = 0.0, diag = 0.0;
    for (int i = t; i < NS; i += 1024) {
        double u = (double)u_in[i];
        su += u;
        sw += u * (u + (double)b_in[i]);
    }
    for (int k = t; k < NW - 1; k += 1024) {
        size_t idx = (size_t)k * NW + (size_t)k + 1;
        diag += (double)bigram[idx] + (double)bias[idx];
    }
#pragma unroll
    for (int off = 32; off; off >>= 1) {
        su   += __shfl_down(su, off);
        sw   += __shfl_down(sw, off);
        diag += __shfl_down(diag, off);
    }
    __shared__ double s1[16], s2[16], s3[16];
    if ((t & 63) == 0) { int w = t >> 6; s1[w] = su; s2[w] = sw; s3[w] = diag; }
    __syncthreads();
    if (t == 0) {
        for (int w = 1; w < 16; ++w) { su += s1[w]; sw += s2[w]; diag += s3[w]; }
        double C = (double)start[0] + (double)endv[NW - 1] + diag;
        out[0] = (float)(sw / su - C);
    }
}

// ===========================================================================
extern "C" void kernel_launch(void* const* d_in, const int* in_sizes, int n_in,
                              void* d_out, int out_size, void* d_ws, size_t ws_size,
                              hipStream_t stream) {
    const float* bigram  = (const float*)d_in[0];
    const float* start   = (const float*)d_in[1];
    const float* endv    = (const float*)d_in[2];
    const float* bias    = (const float*)d_in[3];
    const int*   samples = (const int*)d_in[4];
    float* out = (float*)d_out;

    // primary ws layout
    size_t off = 0;
    size_t tab_off  = off; off += (size_t)NW * NW * 2;    // 8 MB u16 table
    off = (off + 255) & ~(size_t)255;
    size_t keys_off = off; off += (size_t)NS * NW * 2;    // 32 MB u16 keys
    off = (off + 255) & ~(size_t)255;
    size_t ocs_off  = off; off += (size_t)NS * NSL * 4;   // 4 MB oc sample-major
    off = (off + 255) & ~(size_t)255;
    size_t ocq_off  = off; off += (size_t)NS * NSL * 4;   // 4 MB oc slice-major
    off = (off + 255) & ~(size_t)255;
    size_t fl_off   = off; off += (size_t)NS * 2 * 4;     // 64 KB first/last
    off = (off + 255) & ~(size_t)255;
    size_t acc_off  = off; off += (size_t)NS * 8;         // 64 KB packed acc
    off = (off + 255) & ~(size_t)255;
    size_t part_off = off; off += (size_t)32 * 3 * 8;     // 768 B fp64 partials
    size_t need_primary = off;

    if (ws_size >= need_primary) {
        unsigned short*     tab   = (unsigned short*)((char*)d_ws + tab_off);
        unsigned short*     gkeys = (unsigned short*)((char*)d_ws + keys_off);
        unsigned*           oc_s  = (unsigned*)((char*)d_ws + ocs_off);
        unsigned*           oc_q  = (unsigned*)((char*)d_ws + ocq_off);
        int*                fl    = (int*)((char*)d_ws + fl_off);
        unsigned long long* acc   = (unsigned long long*)((char*)d_ws + acc_off);
        double*             part  = (double*)((char*)d_ws + part_off);

        hipMemsetAsync(acc, 0, (size_t)NS * 8, stream);
        build_table8_kernel<<<2048, 256, 0, stream>>>(
            (const f32x4*)bigram, (const f32x4*)bias, (u16x4*)tab, NW * NW / 4);
        bucket3_kernel<<<NS / 4, 256, 0, stream>>>(
            (const i32x4*)samples, gkeys, oc_s, fl);
        transpose_oc_kernel<<<dim3(NS / 64, NSL / 32), 256, 0, stream>>>(oc_s, oc_q);
        gather6_kernel<<<dim3(NSL, NS / 1024), 1024, 0, stream>>>(
            tab, gkeys, oc_q, acc);
        finalize_part_kernel<<<32, 256, 0, stream>>>(
            bigram, bias, start, endv, acc, fl, part);
        finalize_final_kernel<<<1, 64, 0, stream>>>(start, endv, part, out);
        return;
    }

    // fallback: round-1 structure
    float* u_out = (float*)d_ws;
    float* b_out = u_out + NS;
    size_t comb_off = ((size_t)NS * 2 * sizeof(float) + 255) & ~(size_t)255;
    size_t comb_bytes = (size_t)NW * NW * sizeof(float2);
    bool use_comb = (ws_size >= comb_off + comb_bytes);
    if (use_comb) {
        float2* comb = (float2*)((char*)d_ws + comb_off);
        interleave_kernel<<<4096, 256, 0, stream>>>(bigram, bias, comb);
        sample_kernel<true><<<NS, 256, 0, stream>>>(comb, bigram, bias, start, endv,
                                                    samples, u_out, b_out);
    } else {
        sample_kernel<false><<<NS, 256, 0, stream>>>(nullptr, bigram, bias, start, endv,
                                                     samples, u_out, b_out);
    }
    finalize_kernel<<<1, 1024, 0, stream>>>(bigram, bias, start, endv, u_out, b_out, out);
}